// Round 1
// baseline (1060.227 us; speedup 1.0000x reference)
//
#include <hip/hip_runtime.h>

#define BATCH 4
#define NPTS  4096
#define NQ    8192
#define KNN   20
#define RES   64
#define FDIM  6

// ws layout: [grid: BATCH*RES^3*FDIM floats][feat: BATCH*NPTS*FDIM floats]
#define GRID_ELEMS ((size_t)BATCH * RES * RES * RES * FDIM)
#define GRID_BYTES (GRID_ELEMS * sizeof(float))

// ---------------------------------------------------------------------------
// Trilinear corner setup, faithful to reference _corners():
//   ind0 = floor(p*64); ind1 = ceil(p*64) mod 64
//   corner c (meshgrid ij order): bits (c>>2&1, c>>1&1, c&1) per dim
//   weight factor dim d: bit==0 -> |p - (ind0+1)/64|*64 ; bit==1 -> |p - ind0/64|*64
// ---------------------------------------------------------------------------
__device__ __forceinline__ void corner_setup(float px, float py, float pz,
                                             int i0[3], int i1[3],
                                             float w0[3], float w1[3]) {
    float p[3] = {px, py, pz};
    #pragma unroll
    for (int d = 0; d < 3; ++d) {
        float f  = p[d] * 64.0f;          // exact (power-of-2 scale)
        float fl = floorf(f);
        i0[d] = (int)fl;
        i1[d] = ((int)ceilf(f)) & (RES - 1);   // ceil in [0,64] -> mod 64
        float x0 = fl / 64.0f;
        float x1 = (fl + 1.0f) / 64.0f;
        w0[d] = fabsf(p[d] - x1) * 64.0f;      // used when corner bit == 0
        w1[d] = fabsf(p[d] - x0) * 64.0f;      // used when corner bit == 1
    }
}

// ---------------------------------------------------------------------------
// Kernel A: brute-force kNN (k=20, includes self) + EdgeConv max-pool feature.
// One thread per point; one block = 64 points of one batch; batch coords in LDS.
// ---------------------------------------------------------------------------
__global__ __launch_bounds__(64) void knn_feat_kernel(const float* __restrict__ pts,
                                                      float* __restrict__ feat) {
    const int blocks_per_batch = NPTS / 64;          // 64
    const int b  = blockIdx.x / blocks_per_batch;
    const int p0 = (blockIdx.x % blocks_per_batch) * 64;
    const int t  = threadIdx.x;

    __shared__ float sh[NPTS * 3];                   // 48 KB
    __shared__ float sd[64 * KNN];                   // 5 KB
    __shared__ int   si[64 * KNN];                   // 5 KB

    const float* pb = pts + (size_t)b * NPTS * 3;
    for (int i = t; i < NPTS * 3; i += 64) sh[i] = pb[i];
    __syncthreads();

    const int pi = p0 + t;
    const float px = sh[pi * 3 + 0];
    const float py = sh[pi * 3 + 1];
    const float pz = sh[pi * 3 + 2];

    float* myd = sd + t * KNN;
    int*   myi = si + t * KNN;
    #pragma unroll
    for (int s = 0; s < KNN; ++s) { myd[s] = 3.4e38f; myi[s] = 0; }
    float worst = 3.4e38f;
    int   wslot = 0;

    for (int j = 0; j < NPTS; ++j) {
        float dx = sh[j * 3 + 0] - px;
        float dy = sh[j * 3 + 1] - py;
        float dz = sh[j * 3 + 2] - pz;
        float d2 = dx * dx + dy * dy + dz * dz;
        if (d2 < worst) {
            myd[wslot] = d2;
            myi[wslot] = j;
            float w = -1.0f; int ws = 0;
            #pragma unroll
            for (int s = 0; s < KNN; ++s) {
                if (myd[s] > w) { w = myd[s]; ws = s; }
            }
            worst = w; wslot = ws;
        }
    }

    // max over the 20 nearest of (neighbor - self), componentwise (self gives 0)
    float mx = -3.4e38f, my = -3.4e38f, mz = -3.4e38f;
    #pragma unroll
    for (int s = 0; s < KNN; ++s) {
        int j = myi[s];
        mx = fmaxf(mx, sh[j * 3 + 0] - px);
        my = fmaxf(my, sh[j * 3 + 1] - py);
        mz = fmaxf(mz, sh[j * 3 + 2] - pz);
    }

    float* f = feat + ((size_t)b * NPTS + pi) * FDIM;
    f[0] = mx; f[1] = my; f[2] = mz;
    f[3] = px; f[4] = py; f[5] = pz;
}

// ---------------------------------------------------------------------------
// Kernel B: trilinear scatter-add of feat onto (B, 64,64,64, 6) grid.
// One thread per point, 48 atomicAdds each.
// ---------------------------------------------------------------------------
__global__ __launch_bounds__(256) void rasterize_kernel(const float* __restrict__ pts,
                                                        const float* __restrict__ feat,
                                                        float* __restrict__ grid) {
    int gid = blockIdx.x * blockDim.x + threadIdx.x;   // 0 .. B*NPTS-1
    if (gid >= BATCH * NPTS) return;
    int b = gid / NPTS;

    const float* p = pts + (size_t)gid * 3;
    float px = p[0], py = p[1], pz = p[2];

    int i0[3], i1[3];
    float w0[3], w1[3];
    corner_setup(px, py, pz, i0, i1, w0, w1);

    float fv[FDIM];
    const float* f = feat + (size_t)gid * FDIM;
    #pragma unroll
    for (int c = 0; c < FDIM; ++c) fv[c] = f[c];

    float* gb = grid + (size_t)b * RES * RES * RES * FDIM;
    #pragma unroll
    for (int c = 0; c < 8; ++c) {
        int bx = (c >> 2) & 1, by = (c >> 1) & 1, bz = c & 1;
        int ix = bx ? i1[0] : i0[0];
        int iy = by ? i1[1] : i0[1];
        int iz = bz ? i1[2] : i0[2];
        float w = (bx ? w1[0] : w0[0]) * (by ? w1[1] : w0[1]) * (bz ? w1[2] : w0[2]);
        size_t base = ((size_t)(ix * RES + iy) * RES + iz) * FDIM;
        #pragma unroll
        for (int ch = 0; ch < FDIM; ++ch)
            atomicAdd(&gb[base + ch], w * fv[ch]);
    }
}

// ---------------------------------------------------------------------------
// Kernel C: trilinear gather at query points.
// ---------------------------------------------------------------------------
__global__ __launch_bounds__(256) void interp_kernel(const float* __restrict__ query,
                                                     const float* __restrict__ grid,
                                                     float* __restrict__ out) {
    int gid = blockIdx.x * blockDim.x + threadIdx.x;   // 0 .. B*NQ-1
    if (gid >= BATCH * NQ) return;
    int b = gid / NQ;

    const float* q = query + (size_t)gid * 3;
    float qx = q[0], qy = q[1], qz = q[2];

    int i0[3], i1[3];
    float w0[3], w1[3];
    corner_setup(qx, qy, qz, i0, i1, w0, w1);

    float acc[FDIM];
    #pragma unroll
    for (int ch = 0; ch < FDIM; ++ch) acc[ch] = 0.0f;

    const float* gb = grid + (size_t)b * RES * RES * RES * FDIM;
    #pragma unroll
    for (int c = 0; c < 8; ++c) {
        int bx = (c >> 2) & 1, by = (c >> 1) & 1, bz = c & 1;
        int ix = bx ? i1[0] : i0[0];
        int iy = by ? i1[1] : i0[1];
        int iz = bz ? i1[2] : i0[2];
        float w = (bx ? w1[0] : w0[0]) * (by ? w1[1] : w0[1]) * (bz ? w1[2] : w0[2]);
        const float* g = gb + ((size_t)(ix * RES + iy) * RES + iz) * FDIM;
        #pragma unroll
        for (int ch = 0; ch < FDIM; ++ch)
            acc[ch] += w * g[ch];
    }

    float* o = out + (size_t)gid * FDIM;
    #pragma unroll
    for (int ch = 0; ch < FDIM; ++ch) o[ch] = acc[ch];
}

// ---------------------------------------------------------------------------
extern "C" void kernel_launch(void* const* d_in, const int* in_sizes, int n_in,
                              void* d_out, int out_size, void* d_ws, size_t ws_size,
                              hipStream_t stream) {
    const float* pts   = (const float*)d_in[0];   // (4, 4096, 3)
    const float* query = (const float*)d_in[1];   // (4, 8192, 3)
    float* out  = (float*)d_out;                  // (4, 8192, 6)

    float* grid = (float*)d_ws;
    float* feat = (float*)((char*)d_ws + GRID_BYTES);

    hipMemsetAsync(grid, 0, GRID_BYTES, stream);

    knn_feat_kernel<<<(BATCH * NPTS) / 64, 64, 0, stream>>>(pts, feat);

    rasterize_kernel<<<(BATCH * NPTS + 255) / 256, 256, 0, stream>>>(pts, feat, grid);

    interp_kernel<<<(BATCH * NQ + 255) / 256, 256, 0, stream>>>(query, grid, out);
}

// Round 2
// 240.056 us; speedup vs baseline: 4.4166x; 4.4166x over previous
//
#include <hip/hip_runtime.h>

#define BATCH 4
#define NPTS  4096
#define NQ    8192
#define KNN   20
#define RES   64
#define FDIM  6
#define NSEG  8
#define SEG   (NPTS / NSEG)        // 512 candidates per segment
#define PPB   256                  // points per block (A1/A3)
#define PGROUPS (NPTS / PPB)       // 16

// ---------------- ws layout ----------------
// [0, GRID_BYTES)              grid (B,64,64,64,6)  — zeroed AFTER A3, used by B,C
//   t20 aliases [0, 10.49MB)   per-segment sorted top-20 dists (consumed by A2 pre-memset)
// [GRID_BYTES, +64KB)          tval : 20th-NN dist^2 per point
// [GRID_BYTES+64KB, +192KB)    cmax : int-encoded masked coord max per point (3 ints)
#define GRID_ELEMS ((size_t)BATCH * RES * RES * RES * FDIM)
#define GRID_BYTES (GRID_ELEMS * sizeof(float))           // 25,165,824
#define TVAL_BYTES ((size_t)BATCH * NPTS * sizeof(float)) //     65,536
#define CMAX_BYTES ((size_t)BATCH * NPTS * 3 * sizeof(int)) //  196,608

// Bit-identical distance in A1 and A3 (explicit fmaf sequence, no re-association).
__device__ __forceinline__ float dist2(float4 c, float px, float py, float pz) {
    float dx = c.x - px, dy = c.y - py, dz = c.z - pz;
    return __builtin_fmaf(dz, dz, __builtin_fmaf(dy, dy, dx * dx));
}

__device__ __forceinline__ void stage_seg(const float* __restrict__ pts, int b, int seg,
                                          float4* shc, int tid) {
    const float* src = pts + ((size_t)b * NPTS + (size_t)seg * SEG) * 3;
    for (int i = tid; i < SEG; i += PPB)
        shc[i] = make_float4(src[i * 3 + 0], src[i * 3 + 1], src[i * 3 + 2], 0.0f);
    __syncthreads();
}

// Branchless insert of pre-sorted pair (lo<=hi) into ascending 20-reg list.
#define PAIR_INSERT(d, lo, hi)                                   \
    _Pragma("unroll")                                            \
    for (int s = 0; s < KNN; ++s) {                              \
        float a_ = d[s];                                         \
        float mn_ = fminf(fminf(a_, lo), hi);                    \
        float md_ = __builtin_amdgcn_fmed3f(a_, lo, hi);         \
        float mx_ = fmaxf(fmaxf(a_, lo), hi);                    \
        d[s] = mn_; lo = md_; hi = mx_;                          \
    }

// ---------------------------------------------------------------------------
// A1: per-(point, segment) top-20 distances via branchless min3/med3/max3 chain.
// ---------------------------------------------------------------------------
__global__ __launch_bounds__(PPB) void knn_seg_kernel(const float* __restrict__ pts,
                                                      float* __restrict__ t20) {
    const int bx  = blockIdx.x;
    const int seg = bx % NSEG;
    const int pg  = (bx / NSEG) % PGROUPS;
    const int b   = bx / (NSEG * PGROUPS);
    const int tid = threadIdx.x;

    __shared__ float4 shc[SEG];          // 8 KB
    stage_seg(pts, b, seg, shc, tid);

    const int pi = pg * PPB + tid;
    const float* pp = pts + ((size_t)b * NPTS + pi) * 3;
    const float px = pp[0], py = pp[1], pz = pp[2];

    float d[KNN];
    #pragma unroll
    for (int s = 0; s < KNN; ++s) d[s] = 3.4e38f;

    for (int j = 0; j < SEG; j += 2) {
        float da = dist2(shc[j], px, py, pz);
        float db = dist2(shc[j + 1], px, py, pz);
        float lo = fminf(da, db), hi = fmaxf(da, db);
        PAIR_INSERT(d, lo, hi)
    }

    float* o = t20 + ((size_t)(b * NPTS + pi) * NSEG + seg) * KNN;
    ((float4*)o)[0] = make_float4(d[0], d[1], d[2], d[3]);
    ((float4*)o)[1] = make_float4(d[4], d[5], d[6], d[7]);
    ((float4*)o)[2] = make_float4(d[8], d[9], d[10], d[11]);
    ((float4*)o)[3] = make_float4(d[12], d[13], d[14], d[15]);
    ((float4*)o)[4] = make_float4(d[16], d[17], d[18], d[19]);
}

// ---------------------------------------------------------------------------
// A2: merge 8 sorted 20-lists per point -> exact 20th-smallest dist^2.
// ---------------------------------------------------------------------------
__global__ __launch_bounds__(256) void merge_t_kernel(const float* __restrict__ t20,
                                                      float* __restrict__ tval) {
    const int pt = blockIdx.x * 256 + threadIdx.x;       // 0 .. B*NPTS-1
    const float4* src = (const float4*)(t20 + (size_t)pt * NSEG * KNN);

    float d[KNN];
    #pragma unroll
    for (int s = 0; s < KNN; ++s) d[s] = 3.4e38f;

    for (int i = 0; i < (NSEG * KNN) / 4; ++i) {         // 40 float4s
        float4 v = src[i];
        float lo = fminf(v.x, v.y), hi = fmaxf(v.x, v.y);
        PAIR_INSERT(d, lo, hi)
        lo = fminf(v.z, v.w); hi = fmaxf(v.z, v.w);
        PAIR_INSERT(d, lo, hi)
    }
    tval[pt] = d[KNN - 1];
}

// ---------------------------------------------------------------------------
// A3: per-(point, segment) masked coord max (d2 <= t), merged via int atomicMax
// (valid: coords are positive floats; cmax pre-zeroed).
// ---------------------------------------------------------------------------
__global__ __launch_bounds__(PPB) void maxfeat_kernel(const float* __restrict__ pts,
                                                      const float* __restrict__ tval,
                                                      int* __restrict__ cmax) {
    const int bx  = blockIdx.x;
    const int seg = bx % NSEG;
    const int pg  = (bx / NSEG) % PGROUPS;
    const int b   = bx / (NSEG * PGROUPS);
    const int tid = threadIdx.x;

    __shared__ float4 shc[SEG];
    stage_seg(pts, b, seg, shc, tid);

    const int pi = pg * PPB + tid;
    const int pt = b * NPTS + pi;
    const float* pp = pts + (size_t)pt * 3;
    const float px = pp[0], py = pp[1], pz = pp[2];
    const float t = tval[pt];

    float mx = -3.4e38f, my = -3.4e38f, mz = -3.4e38f;
    for (int j = 0; j < SEG; ++j) {
        float4 c = shc[j];
        float d2 = dist2(c, px, py, pz);
        bool in = (d2 <= t);
        mx = fmaxf(mx, in ? c.x : -3.4e38f);
        my = fmaxf(my, in ? c.y : -3.4e38f);
        mz = fmaxf(mz, in ? c.z : -3.4e38f);
    }

    int* cm = cmax + (size_t)pt * 3;
    atomicMax(&cm[0], __float_as_int(mx));
    atomicMax(&cm[1], __float_as_int(my));
    atomicMax(&cm[2], __float_as_int(mz));
}

// ---------------------------------------------------------------------------
// Trilinear corner setup, faithful to reference _corners().
// ---------------------------------------------------------------------------
__device__ __forceinline__ void corner_setup(float px, float py, float pz,
                                             int i0[3], int i1[3],
                                             float w0[3], float w1[3]) {
    float p[3] = {px, py, pz};
    #pragma unroll
    for (int d = 0; d < 3; ++d) {
        float f  = p[d] * 64.0f;
        float fl = floorf(f);
        i0[d] = (int)fl;
        i1[d] = ((int)ceilf(f)) & (RES - 1);
        float x0 = fl / 64.0f;
        float x1 = (fl + 1.0f) / 64.0f;
        w0[d] = fabsf(p[d] - x1) * 64.0f;   // corner bit == 0
        w1[d] = fabsf(p[d] - x0) * 64.0f;   // corner bit == 1
    }
}

// ---------------------------------------------------------------------------
// B: feature from cmax + trilinear scatter-add onto grid.
// ---------------------------------------------------------------------------
__global__ __launch_bounds__(256) void rasterize_kernel(const float* __restrict__ pts,
                                                        const int* __restrict__ cmax,
                                                        float* __restrict__ grid) {
    int gid = blockIdx.x * blockDim.x + threadIdx.x;     // 0 .. B*NPTS-1
    if (gid >= BATCH * NPTS) return;
    int b = gid / NPTS;

    const float* p = pts + (size_t)gid * 3;
    float px = p[0], py = p[1], pz = p[2];

    const int* cm = cmax + (size_t)gid * 3;
    float fv[FDIM];
    fv[0] = __int_as_float(cm[0]) - px;
    fv[1] = __int_as_float(cm[1]) - py;
    fv[2] = __int_as_float(cm[2]) - pz;
    fv[3] = px; fv[4] = py; fv[5] = pz;

    int i0[3], i1[3];
    float w0[3], w1[3];
    corner_setup(px, py, pz, i0, i1, w0, w1);

    float* gb = grid + (size_t)b * RES * RES * RES * FDIM;
    #pragma unroll
    for (int c = 0; c < 8; ++c) {
        int bx = (c >> 2) & 1, by = (c >> 1) & 1, bz = c & 1;
        int ix = bx ? i1[0] : i0[0];
        int iy = by ? i1[1] : i0[1];
        int iz = bz ? i1[2] : i0[2];
        float w = (bx ? w1[0] : w0[0]) * (by ? w1[1] : w0[1]) * (bz ? w1[2] : w0[2]);
        size_t base = ((size_t)(ix * RES + iy) * RES + iz) * FDIM;
        #pragma unroll
        for (int ch = 0; ch < FDIM; ++ch)
            atomicAdd(&gb[base + ch], w * fv[ch]);
    }
}

// ---------------------------------------------------------------------------
// C: trilinear gather at query points (float2-vectorized cell loads).
// ---------------------------------------------------------------------------
__global__ __launch_bounds__(256) void interp_kernel(const float* __restrict__ query,
                                                     const float* __restrict__ grid,
                                                     float* __restrict__ out) {
    int gid = blockIdx.x * blockDim.x + threadIdx.x;     // 0 .. B*NQ-1
    if (gid >= BATCH * NQ) return;
    int b = gid / NQ;

    const float* q = query + (size_t)gid * 3;
    float qx = q[0], qy = q[1], qz = q[2];

    int i0[3], i1[3];
    float w0[3], w1[3];
    corner_setup(qx, qy, qz, i0, i1, w0, w1);

    float acc[FDIM];
    #pragma unroll
    for (int ch = 0; ch < FDIM; ++ch) acc[ch] = 0.0f;

    const float* gb = grid + (size_t)b * RES * RES * RES * FDIM;
    #pragma unroll
    for (int c = 0; c < 8; ++c) {
        int bx = (c >> 2) & 1, by = (c >> 1) & 1, bz = c & 1;
        int ix = bx ? i1[0] : i0[0];
        int iy = by ? i1[1] : i0[1];
        int iz = bz ? i1[2] : i0[2];
        float w = (bx ? w1[0] : w0[0]) * (by ? w1[1] : w0[1]) * (bz ? w1[2] : w0[2]);
        const float2* g = (const float2*)(gb + ((size_t)(ix * RES + iy) * RES + iz) * FDIM);
        float2 g0 = g[0], g1 = g[1], g2 = g[2];
        acc[0] += w * g0.x; acc[1] += w * g0.y;
        acc[2] += w * g1.x; acc[3] += w * g1.y;
        acc[4] += w * g2.x; acc[5] += w * g2.y;
    }

    float* o = out + (size_t)gid * FDIM;
    #pragma unroll
    for (int ch = 0; ch < FDIM; ++ch) o[ch] = acc[ch];
}

// ---------------------------------------------------------------------------
extern "C" void kernel_launch(void* const* d_in, const int* in_sizes, int n_in,
                              void* d_out, int out_size, void* d_ws, size_t ws_size,
                              hipStream_t stream) {
    const float* pts   = (const float*)d_in[0];   // (4, 4096, 3)
    const float* query = (const float*)d_in[1];   // (4, 8192, 3)
    float* out = (float*)d_out;                   // (4, 8192, 6)

    float* grid = (float*)d_ws;
    float* t20  = (float*)d_ws;                                  // aliases grid (pre-memset)
    float* tval = (float*)((char*)d_ws + GRID_BYTES);
    int*   cmax = (int*)((char*)d_ws + GRID_BYTES + TVAL_BYTES);

    hipMemsetAsync(cmax, 0, CMAX_BYTES, stream);

    knn_seg_kernel<<<BATCH * PGROUPS * NSEG, PPB, 0, stream>>>(pts, t20);
    merge_t_kernel<<<(BATCH * NPTS) / 256, 256, 0, stream>>>(t20, tval);
    maxfeat_kernel<<<BATCH * PGROUPS * NSEG, PPB, 0, stream>>>(pts, tval, cmax);

    hipMemsetAsync(grid, 0, GRID_BYTES, stream);   // after A2/A3 consumed the alias

    rasterize_kernel<<<(BATCH * NPTS + 255) / 256, 256, 0, stream>>>(pts, cmax, grid);
    interp_kernel<<<(BATCH * NQ + 255) / 256, 256, 0, stream>>>(query, grid, out);
}

// Round 5
// 224.248 us; speedup vs baseline: 4.7279x; 1.0705x over previous
//
#include <hip/hip_runtime.h>

#define BATCH 4
#define NPTS  4096
#define NQ    8192
#define KNN   20
#define RES   64
#define FDIM  6

#define NSEG    32                 // candidate ranges per batch
#define SEG     (NPTS / NSEG)      // 128 candidates per range
#define PGROUPS (NPTS / 256)       // 16 point-groups of 256

#define CAP 128                    // survivor capacity per point
// r0 = cbrt(60 / (4096 * 4/3*pi)) : radius capturing ~60 expected neighbours interior
#define R0 0.15179f

// ---------------- ws layout ----------------
// [0, GRID_BYTES)   : survivor arrays sd (8.39MB) + si (4.19MB), consumed by K2,
//                     THEN the region is memset and reused as grid (B,64,64,64,6).
// [GRID_BYTES,+64K) : cnt (B*NPTS ints)
// feat (B*NPTS*6 floats = 384KB) lives in the FRONT OF d_out: written by K2,
// read by rasterize, then fully overwritten by interp's final output.
#define GRID_ELEMS ((size_t)BATCH * RES * RES * RES * FDIM)
#define GRID_BYTES (GRID_ELEMS * sizeof(float))                   // 25,165,824
#define SD_BYTES   ((size_t)BATCH * NPTS * CAP * sizeof(float))   //  8,388,608
#define CNT_BYTES  ((size_t)BATCH * NPTS * sizeof(int))           //     65,536

__device__ __forceinline__ float dist2s(float cx, float cy, float cz,
                                        float px, float py, float pz) {
    float dx = cx - px, dy = cy - py, dz = cz - pz;
    return __builtin_fmaf(dz, dz, __builtin_fmaf(dy, dy, dx * dx));
}

// Branchless insert of pre-sorted pair (lo<=hi) into ascending 20-reg list.
#define PAIR_INSERT(d, lo, hi)                                   \
    _Pragma("unroll")                                            \
    for (int s = 0; s < KNN; ++s) {                              \
        float a_ = d[s];                                         \
        float mn_ = fminf(fminf(a_, lo), hi);                    \
        float md_ = __builtin_amdgcn_fmed3f(a_, lo, hi);         \
        float mx_ = fmaxf(fmaxf(a_, lo), hi);                    \
        d[s] = mn_; lo = md_; hi = mx_;                          \
    }

#define SINGLE_INSERT(d, v)                                      \
    _Pragma("unroll")                                            \
    for (int s = 0; s < KNN; ++s) {                              \
        float a_ = d[s];                                         \
        d[s] = fminf(a_, v); v = fmaxf(a_, v);                   \
    }

// ---------------------------------------------------------------------------
// K1: radius filter. Block = 256 points x one 128-candidate range (staged in LDS).
// Survivors (d2 <= tau(p)) appended to per-point global list.
// Exactness does NOT depend on tau being right — only fallback frequency does.
// ---------------------------------------------------------------------------
__global__ __launch_bounds__(256) void filter_kernel(const float* __restrict__ pts,
                                                     int* __restrict__ cnt,
                                                     float* __restrict__ sd,
                                                     unsigned short* __restrict__ si) {
    const int bx  = blockIdx.x;
    const int seg = bx % NSEG;
    const int pg  = (bx / NSEG) % PGROUPS;
    const int b   = bx / (NSEG * PGROUPS);
    const int tid = threadIdx.x;

    __shared__ float4 shc[SEG];                 // 2 KB
    {
        const float* src = pts + ((size_t)b * NPTS + (size_t)seg * SEG) * 3;
        if (tid < SEG)
            shc[tid] = make_float4(src[tid * 3 + 0], src[tid * 3 + 1], src[tid * 3 + 2], 0.f);
    }
    __syncthreads();

    const int pi = pg * 256 + tid;
    const int pt = b * NPTS + pi;
    const float* pp = pts + (size_t)pt * 3;
    const float px = pp[0], py = pp[1], pz = pp[2];

    // tau(p): radius capturing ~60*1.16 expected candidates, boundary-corrected
    // via box-clip fraction, 2 fixed-point iterations + 5% safety.
    float r = R0;
    #pragma unroll
    for (int it = 0; it < 2; ++it) {
        float ex = fminf(px + r, 1.f) - fmaxf(px - r, 0.f);
        float ey = fminf(py + r, 1.f) - fmaxf(py - r, 0.f);
        float ez = fminf(pz + r, 1.f) - fmaxf(pz - r, 0.f);
        float frac = (ex * ey * ez) / (8.f * r * r * r);
        r = R0 * __powf(frac, -1.f / 3.f);
    }
    r *= 1.05f;
    const float tau = r * r;

    const int base = seg * SEG;
    #pragma unroll 4
    for (int j = 0; j < SEG; ++j) {
        float4 c = shc[j];
        float d2 = dist2s(c.x, c.y, c.z, px, py, pz);
        if (d2 <= tau) {
            int slot = atomicAdd(&cnt[pt], 1);
            if (slot < CAP) {
                sd[(size_t)pt * CAP + slot] = d2;
                si[(size_t)pt * CAP + slot] = (unsigned short)(base + j);
            }
        }
    }
}

// ---------------------------------------------------------------------------
// K2: per point — chain survivors -> exact 20th dist t, then masked coord-max
// over survivors -> EdgeConv feature (6 floats). Exact full-scan fallback if
// cnt<20 or cnt>CAP (expected: never fires).
// ---------------------------------------------------------------------------
__global__ __launch_bounds__(64) void select_kernel(const float* __restrict__ pts,
                                                    const int* __restrict__ cnt,
                                                    const float* __restrict__ sd,
                                                    const unsigned short* __restrict__ si,
                                                    float* __restrict__ feat) {
    const int pt = blockIdx.x * 64 + threadIdx.x;        // 0 .. B*NPTS-1
    const int b  = pt / NPTS;
    const float* pp = pts + (size_t)pt * 3;
    const float px = pp[0], py = pp[1], pz = pp[2];
    const float* pb = pts + (size_t)b * NPTS * 3;

    float d[KNN];
    #pragma unroll
    for (int s = 0; s < KNN; ++s) d[s] = 3.4e38f;

    float mx = -3.4e38f, my = -3.4e38f, mz = -3.4e38f;
    const int n = cnt[pt];

    if (n >= KNN && n <= CAP) {
        const float* myd = sd + (size_t)pt * CAP;        // 512B-aligned
        int i = 0;
        for (; i + 4 <= n; i += 4) {
            float4 v = *(const float4*)(myd + i);
            float lo = fminf(v.x, v.y), hi = fmaxf(v.x, v.y);
            PAIR_INSERT(d, lo, hi)
            lo = fminf(v.z, v.w); hi = fmaxf(v.z, v.w);
            PAIR_INSERT(d, lo, hi)
        }
        for (; i < n; ++i) {
            float v = myd[i];
            SINGLE_INSERT(d, v)
        }
        const float t = d[KNN - 1];
        const unsigned short* myi = si + (size_t)pt * CAP;
        for (int k = 0; k < n; ++k) {
            if (myd[k] <= t) {
                int j = myi[k];
                const float* c = pb + j * 3;
                mx = fmaxf(mx, c[0]); my = fmaxf(my, c[1]); mz = fmaxf(mz, c[2]);
            }
        }
    } else {
        // exact fallback: full scan (guaranteed correct, expected never)
        for (int j = 0; j < NPTS; j += 2) {
            const float* c0 = pb + j * 3;
            float da = dist2s(c0[0], c0[1], c0[2], px, py, pz);
            float db = dist2s(c0[3], c0[4], c0[5], px, py, pz);
            float lo = fminf(da, db), hi = fmaxf(da, db);
            PAIR_INSERT(d, lo, hi)
        }
        const float t = d[KNN - 1];
        for (int j = 0; j < NPTS; ++j) {
            const float* c = pb + j * 3;
            float d2 = dist2s(c[0], c[1], c[2], px, py, pz);
            if (d2 <= t) {
                mx = fmaxf(mx, c[0]); my = fmaxf(my, c[1]); mz = fmaxf(mz, c[2]);
            }
        }
    }

    float* f = feat + (size_t)pt * FDIM;
    f[0] = mx - px; f[1] = my - py; f[2] = mz - pz;
    f[3] = px; f[4] = py; f[5] = pz;
}

// ---------------------------------------------------------------------------
// Trilinear corner setup, faithful to reference _corners().
// ---------------------------------------------------------------------------
__device__ __forceinline__ void corner_setup(float px, float py, float pz,
                                             int i0[3], int i1[3],
                                             float w0[3], float w1[3]) {
    float p[3] = {px, py, pz};
    #pragma unroll
    for (int d = 0; d < 3; ++d) {
        float f  = p[d] * 64.0f;
        float fl = floorf(f);
        i0[d] = (int)fl;
        i1[d] = ((int)ceilf(f)) & (RES - 1);
        float x0 = fl / 64.0f;
        float x1 = (fl + 1.0f) / 64.0f;
        w0[d] = fabsf(p[d] - x1) * 64.0f;   // corner bit == 0
        w1[d] = fabsf(p[d] - x0) * 64.0f;   // corner bit == 1
    }
}

// ---------------------------------------------------------------------------
// B: trilinear scatter-add of feat onto grid.
// ---------------------------------------------------------------------------
__global__ __launch_bounds__(64) void rasterize_kernel(const float* __restrict__ pts,
                                                       const float* __restrict__ feat,
                                                       float* __restrict__ grid) {
    int gid = blockIdx.x * 64 + threadIdx.x;             // 0 .. B*NPTS-1
    int b = gid / NPTS;

    const float* p = pts + (size_t)gid * 3;
    float px = p[0], py = p[1], pz = p[2];

    float fv[FDIM];
    const float* f = feat + (size_t)gid * FDIM;
    #pragma unroll
    for (int c = 0; c < FDIM; ++c) fv[c] = f[c];

    int i0[3], i1[3];
    float w0[3], w1[3];
    corner_setup(px, py, pz, i0, i1, w0, w1);

    float* gb = grid + (size_t)b * RES * RES * RES * FDIM;
    #pragma unroll
    for (int c = 0; c < 8; ++c) {
        int bx = (c >> 2) & 1, by = (c >> 1) & 1, bz = c & 1;
        int ix = bx ? i1[0] : i0[0];
        int iy = by ? i1[1] : i0[1];
        int iz = bz ? i1[2] : i0[2];
        float w = (bx ? w1[0] : w0[0]) * (by ? w1[1] : w0[1]) * (bz ? w1[2] : w0[2]);
        size_t basei = ((size_t)(ix * RES + iy) * RES + iz) * FDIM;
        #pragma unroll
        for (int ch = 0; ch < FDIM; ++ch)
            atomicAdd(&gb[basei + ch], w * fv[ch]);
    }
}

// ---------------------------------------------------------------------------
// C: trilinear gather at query points.
// ---------------------------------------------------------------------------
__global__ __launch_bounds__(64) void interp_kernel(const float* __restrict__ query,
                                                    const float* __restrict__ grid,
                                                    float* __restrict__ out) {
    int gid = blockIdx.x * 64 + threadIdx.x;             // 0 .. B*NQ-1
    int b = gid / NQ;

    const float* q = query + (size_t)gid * 3;
    float qx = q[0], qy = q[1], qz = q[2];

    int i0[3], i1[3];
    float w0[3], w1[3];
    corner_setup(qx, qy, qz, i0, i1, w0, w1);

    float acc[FDIM];
    #pragma unroll
    for (int ch = 0; ch < FDIM; ++ch) acc[ch] = 0.0f;

    const float* gb = grid + (size_t)b * RES * RES * RES * FDIM;
    #pragma unroll
    for (int c = 0; c < 8; ++c) {
        int bx = (c >> 2) & 1, by = (c >> 1) & 1, bz = c & 1;
        int ix = bx ? i1[0] : i0[0];
        int iy = by ? i1[1] : i0[1];
        int iz = bz ? i1[2] : i0[2];
        float w = (bx ? w1[0] : w0[0]) * (by ? w1[1] : w0[1]) * (bz ? w1[2] : w0[2]);
        const float2* g = (const float2*)(gb + ((size_t)(ix * RES + iy) * RES + iz) * FDIM);
        float2 g0 = g[0], g1 = g[1], g2 = g[2];
        acc[0] += w * g0.x; acc[1] += w * g0.y;
        acc[2] += w * g1.x; acc[3] += w * g1.y;
        acc[4] += w * g2.x; acc[5] += w * g2.y;
    }

    float* o = out + (size_t)gid * FDIM;
    #pragma unroll
    for (int ch = 0; ch < FDIM; ++ch) o[ch] = acc[ch];
}

// ---------------------------------------------------------------------------
extern "C" void kernel_launch(void* const* d_in, const int* in_sizes, int n_in,
                              void* d_out, int out_size, void* d_ws, size_t ws_size,
                              hipStream_t stream) {
    const float* pts   = (const float*)d_in[0];   // (4, 4096, 3)
    const float* query = (const float*)d_in[1];   // (4, 8192, 3)
    float* out = (float*)d_out;                   // (4, 8192, 6)

    float*          sd   = (float*)d_ws;                              // aliases grid
    unsigned short* si   = (unsigned short*)((char*)d_ws + SD_BYTES); // aliases grid
    float*          grid = (float*)d_ws;
    int*            cnt  = (int*)((char*)d_ws + GRID_BYTES);
    float*          feat = (float*)d_out;  // front 384KB of d_out; overwritten by interp

    hipMemsetAsync(cnt, 0, CNT_BYTES, stream);

    filter_kernel<<<BATCH * PGROUPS * NSEG, 256, 0, stream>>>(pts, cnt, sd, si);
    select_kernel<<<(BATCH * NPTS) / 64, 64, 0, stream>>>(pts, cnt, sd, si, feat);

    hipMemsetAsync(grid, 0, GRID_BYTES, stream);   // after K2 consumed sd/si alias

    rasterize_kernel<<<(BATCH * NPTS) / 64, 64, 0, stream>>>(pts, feat, grid);
    interp_kernel<<<(BATCH * NQ) / 64, 64, 0, stream>>>(query, grid, out);
}